// Round 11
// baseline (696.236 us; speedup 1.0000x reference)
//
#include <hip/hip_runtime.h>
#include <hip/hip_bf16.h>

#define SCALE 0.17677669529663689f  // 32^-0.5

// ---------------- workspace offsets (in floats), total ~243 MB ----------------
#define OFF_S    0UL          // 33,554,432 (bf16 P lives in row 2nd halves)
#define OFF_XQT  33554432UL   // 4,194,304
#define OFF_XV   37748736UL   // 4,194,304
#define OFF_XKT  41943040UL   // 4,194,304
#define OFF_KQ   46137344UL   // 262,144
#define OFF_KK   46399488UL   // 262,144
#define OFF_KV   46661632UL   // 262,144
#define OFF_KATT 46923776UL   // 262,144
#define OFF_XATT 47185920UL   // 4,194,304
#define OFF_MT   51380224UL   // maskT 4 MB
#define OFF_MORI 52428800UL   // 8192 ints
#define OFF_FLAG 52436992UL   // few ints
#define OFF_ISUM 52445184UL   // 8192 floats (per-(bh,k) 1/softmax-sum)
#define OFF_XKBH 52453376UL   // 4,194,304 floats = 8M u16 (xkT hi bf16 [bh][x][d])
#define OFF_XKBL 56647680UL   // 4,194,304 floats = 8M u16 (lo residual)

__device__ __forceinline__ float b2f(unsigned int u) {
    union { unsigned int i; float f; } v; v.i = u << 16; return v.f;
}
__device__ __forceinline__ unsigned short f2b(float f) {
    __hip_bfloat16 h = __float2bfloat16(f);
    return *(unsigned short*)&h;
}

typedef short bh8 __attribute__((ext_vector_type(8)));   // 8 bf16 (4 VGPR) MFMA frag
typedef float fx4 __attribute__((ext_vector_type(4)));   // 4 f32 MFMA accum

// ---------------- dtype detection ----------------
__global__ __launch_bounds__(256) void detect_kernel(
    const unsigned int* __restrict__ mask, const unsigned int* __restrict__ xf,
    int* __restrict__ flags)
{
    __shared__ unsigned int orv;
    __shared__ int cnt;
    int t = threadIdx.x;
    if (t == 0) { orv = 0u; cnt = 0; }
    __syncthreads();
    if (blockIdx.x == 0) {
        unsigned int v = 0;
        for (int i = t; i < 16384; i += 256) v |= mask[i];
        atomicOr(&orv, v);
        __syncthreads();
        if (t == 0) {
            unsigned int o = orv;
            int f;
            if (o <= 1u || o == 0x3F800000u) f = 0;
            else if (o & 0x00800080u)        f = 2;
            else                             f = 1;
            flags[0] = f;
        }
    } else {
        int c = 0;
        for (int i = t; i < 4096; i += 256) {
            unsigned int h = xf[i] & 0xFFFFu;
            unsigned int e = (h >> 7) & 0xFFu;
            if (h == 0u || (e >= 0x75u && e <= 0x82u)) c++;
        }
        atomicAdd(&cnt, c);
        __syncthreads();
        if (t == 0) flags[1] = (cnt > 3000) ? 1 : 0;
    }
}

// ---------------- qkv128 v2: MFMA GEMM 128x64, split-bf16 precision ----------------
__global__ __launch_bounds__(256) void qkv128_kernel(
    const void* __restrict__ A, const void* __restrict__ W,
    float* __restrict__ oq, float* __restrict__ ok, float* __restrict__ ov,
    const int* __restrict__ flags)
{
    __shared__ __align__(16) unsigned short Ah[128 * 40];
    __shared__ __align__(16) unsigned short Al[128 * 40];
    __shared__ __align__(16) unsigned short Wh[64 * 40];
    __shared__ __align__(16) unsigned short Wl[64 * 40];
    int bf = flags[1];
    const float* A32 = (const float*)A;
    const float* W32 = (const float*)W;
    const unsigned short* A16 = (const unsigned short*)A;
    const unsigned short* W16 = (const unsigned short*)W;
    int m0 = blockIdx.x * 128;
    int n0 = blockIdx.y * 64;
    int sec = n0 >> 8;  // 0=q, 1=k (argmax path), 2=v
    int id = threadIdx.x;
    int w = id >> 6, l = id & 63, g = l >> 4, kl = l & 15;
    fx4 acc[2][4] = {};
    for (int kc = 0; kc < 256; kc += 32) {
        {
            int r = id >> 1, c0 = (id & 1) * 16;
            if (bf) {
                uint4 p0 = *(const uint4*)&A16[(size_t)(m0 + r) * 256 + kc + c0];
                uint4 p1 = *(const uint4*)&A16[(size_t)(m0 + r) * 256 + kc + c0 + 8];
                *(uint4*)&Ah[r * 40 + c0]     = p0;
                *(uint4*)&Ah[r * 40 + c0 + 8] = p1;
                uint4 z = make_uint4(0u, 0u, 0u, 0u);
                *(uint4*)&Al[r * 40 + c0]     = z;
                *(uint4*)&Al[r * 40 + c0 + 8] = z;
            } else {
                const float* ap = &A32[(size_t)(m0 + r) * 256 + kc + c0];
                float4 f0 = *(const float4*)&ap[0];
                float4 f1 = *(const float4*)&ap[4];
                float4 f2v = *(const float4*)&ap[8];
                float4 f3 = *(const float4*)&ap[12];
                float av[16] = {f0.x, f0.y, f0.z, f0.w, f1.x, f1.y, f1.z, f1.w,
                                f2v.x, f2v.y, f2v.z, f2v.w, f3.x, f3.y, f3.z, f3.w};
                unsigned int hw[8], lw[8];
                #pragma unroll
                for (int j = 0; j < 8; j++) {
                    unsigned short h0 = f2b(av[2 * j]), h1 = f2b(av[2 * j + 1]);
                    hw[j] = (unsigned int)h0 | ((unsigned int)h1 << 16);
                    unsigned short q0 = f2b(av[2 * j] - b2f(h0));
                    unsigned short q1 = f2b(av[2 * j + 1] - b2f(h1));
                    lw[j] = (unsigned int)q0 | ((unsigned int)q1 << 16);
                }
                *(uint4*)&Ah[r * 40 + c0]     = make_uint4(hw[0], hw[1], hw[2], hw[3]);
                *(uint4*)&Ah[r * 40 + c0 + 8] = make_uint4(hw[4], hw[5], hw[6], hw[7]);
                *(uint4*)&Al[r * 40 + c0]     = make_uint4(lw[0], lw[1], lw[2], lw[3]);
                *(uint4*)&Al[r * 40 + c0 + 8] = make_uint4(lw[4], lw[5], lw[6], lw[7]);
            }
        }
        {
            int kp = (id >> 4) * 2, c0w = (id & 15) * 4;
            if (bf) {
                uint2 r0 = *(const uint2*)&W16[(size_t)(kc + kp) * 768 + n0 + c0w];
                uint2 r1 = *(const uint2*)&W16[(size_t)(kc + kp + 1) * 768 + n0 + c0w];
                unsigned int e0[4] = {r0.x & 0xFFFFu, r0.x >> 16, r0.y & 0xFFFFu, r0.y >> 16};
                unsigned int e1[4] = {r1.x & 0xFFFFu, r1.x >> 16, r1.y & 0xFFFFu, r1.y >> 16};
                #pragma unroll
                for (int j = 0; j < 4; j++) {
                    *(unsigned int*)&Wh[(c0w + j) * 40 + kp] = e0[j] | (e1[j] << 16);
                    *(unsigned int*)&Wl[(c0w + j) * 40 + kp] = 0u;
                }
            } else {
                float4 w0 = *(const float4*)&W32[(size_t)(kc + kp) * 768 + n0 + c0w];
                float4 w1 = *(const float4*)&W32[(size_t)(kc + kp + 1) * 768 + n0 + c0w];
                float e0[4] = {w0.x, w0.y, w0.z, w0.w};
                float e1[4] = {w1.x, w1.y, w1.z, w1.w};
                #pragma unroll
                for (int j = 0; j < 4; j++) {
                    unsigned short h0 = f2b(e0[j]), h1 = f2b(e1[j]);
                    *(unsigned int*)&Wh[(c0w + j) * 40 + kp] =
                        (unsigned int)h0 | ((unsigned int)h1 << 16);
                    unsigned short q0 = f2b(e0[j] - b2f(h0));
                    unsigned short q1 = f2b(e1[j] - b2f(h1));
                    *(unsigned int*)&Wl[(c0w + j) * 40 + kp] =
                        (unsigned int)q0 | ((unsigned int)q1 << 16);
                }
            }
        }
        __syncthreads();
        bh8 a0h = *(const bh8*)&Ah[(w * 32 + kl) * 40 + g * 8];
        bh8 a1h = *(const bh8*)&Ah[(w * 32 + 16 + kl) * 40 + g * 8];
        if (sec == 1) {
            bh8 a0l = *(const bh8*)&Al[(w * 32 + kl) * 40 + g * 8];
            bh8 a1l = *(const bh8*)&Al[(w * 32 + 16 + kl) * 40 + g * 8];
            #pragma unroll
            for (int nt = 0; nt < 4; nt++) {
                bh8 bhf = *(const bh8*)&Wh[(nt * 16 + kl) * 40 + g * 8];
                bh8 blf = *(const bh8*)&Wl[(nt * 16 + kl) * 40 + g * 8];
                acc[0][nt] = __builtin_amdgcn_mfma_f32_16x16x32_bf16(a0h, bhf, acc[0][nt], 0, 0, 0);
                acc[0][nt] = __builtin_amdgcn_mfma_f32_16x16x32_bf16(a0l, bhf, acc[0][nt], 0, 0, 0);
                acc[0][nt] = __builtin_amdgcn_mfma_f32_16x16x32_bf16(a0h, blf, acc[0][nt], 0, 0, 0);
                acc[1][nt] = __builtin_amdgcn_mfma_f32_16x16x32_bf16(a1h, bhf, acc[1][nt], 0, 0, 0);
                acc[1][nt] = __builtin_amdgcn_mfma_f32_16x16x32_bf16(a1l, bhf, acc[1][nt], 0, 0, 0);
                acc[1][nt] = __builtin_amdgcn_mfma_f32_16x16x32_bf16(a1h, blf, acc[1][nt], 0, 0, 0);
            }
        } else {
            #pragma unroll
            for (int nt = 0; nt < 4; nt++) {
                bh8 bhf = *(const bh8*)&Wh[(nt * 16 + kl) * 40 + g * 8];
                acc[0][nt] = __builtin_amdgcn_mfma_f32_16x16x32_bf16(a0h, bhf, acc[0][nt], 0, 0, 0);
                acc[1][nt] = __builtin_amdgcn_mfma_f32_16x16x32_bf16(a1h, bhf, acc[1][nt], 0, 0, 0);
            }
        }
        __syncthreads();
    }
    int b = m0 >> 12;
    if (sec < 2) {
        float* dstb = (sec == 0) ? oq : ok;
        #pragma unroll
        for (int mt = 0; mt < 2; mt++) {
            int rr0 = (m0 & 4095) + w * 32 + mt * 16 + g * 4;
            #pragma unroll
            for (int nt = 0; nt < 4; nt++) {
                int col = n0 + nt * 16 + kl;
                int hh = (col >> 5) & 7, d = col & 31;
                *(float4*)&dstb[((size_t)(b * 8 + hh) * 32 + d) * 4096 + rr0] =
                    make_float4(acc[mt][nt][0], acc[mt][nt][1], acc[mt][nt][2], acc[mt][nt][3]);
            }
        }
    } else {
        #pragma unroll
        for (int mt = 0; mt < 2; mt++) {
            int rr0 = (m0 & 4095) + w * 32 + mt * 16 + g * 4;
            #pragma unroll
            for (int nt = 0; nt < 4; nt++) {
                int col = n0 + nt * 16 + kl;
                int hh = (col >> 5) & 7, d0 = col & 31;
                size_t base = ((size_t)(b * 8 + hh) * 4096 + rr0) * 32 + d0;
                ov[base]      = acc[mt][nt][0];
                ov[base + 32] = acc[mt][nt][1];
                ov[base + 64] = acc[mt][nt][2];
                ov[base + 96] = acc[mt][nt][3];
            }
        }
    }
}

// ---------------- qkv (mode-1, kernal): 64x64 tile ----------------
__global__ __launch_bounds__(256) void qkv_kernel(
    const void* __restrict__ A, const void* __restrict__ W,
    float* __restrict__ oq, float* __restrict__ ok, float* __restrict__ ov,
    const int* __restrict__ flags)
{
    __shared__ __align__(16) float As[16][68];
    __shared__ __align__(16) float Bs[16][64];
    int bf = flags[1];
    const float* A32 = (const float*)A;
    const float* W32 = (const float*)W;
    const unsigned short* A16 = (const unsigned short*)A;
    const unsigned short* W16 = (const unsigned short*)W;
    int m0 = blockIdx.x * 64;
    int n0 = blockIdx.y * 64;
    int id = threadIdx.x;
    int tm = id >> 4, tn = id & 15;
    float acc[4][4] = {};
    for (int k0 = 0; k0 < 256; k0 += 16) {
        int r = id >> 2, ck = (id & 3) * 4;
        int rk = id >> 4, cn = (id & 15) * 4;
        if (bf) {
            uint2 a2 = *(const uint2*)&A16[(size_t)(m0 + r) * 256 + k0 + ck];
            As[ck + 0][r] = b2f(a2.x & 0xFFFFu); As[ck + 1][r] = b2f(a2.x >> 16);
            As[ck + 2][r] = b2f(a2.y & 0xFFFFu); As[ck + 3][r] = b2f(a2.y >> 16);
            uint2 w2 = *(const uint2*)&W16[(size_t)(k0 + rk) * 768 + n0 + cn];
            Bs[rk][cn + 0] = b2f(w2.x & 0xFFFFu); Bs[rk][cn + 1] = b2f(w2.x >> 16);
            Bs[rk][cn + 2] = b2f(w2.y & 0xFFFFu); Bs[rk][cn + 3] = b2f(w2.y >> 16);
        } else {
            float4 a4 = *(const float4*)&A32[(size_t)(m0 + r) * 256 + k0 + ck];
            As[ck + 0][r] = a4.x; As[ck + 1][r] = a4.y;
            As[ck + 2][r] = a4.z; As[ck + 3][r] = a4.w;
            *(float4*)&Bs[rk][cn] = *(const float4*)&W32[(size_t)(k0 + rk) * 768 + n0 + cn];
        }
        __syncthreads();
        #pragma unroll
        for (int kk = 0; kk < 16; kk++) {
            float4 a = *(const float4*)&As[kk][tm * 4];
            float4 b = *(const float4*)&Bs[kk][tn * 4];
            float av[4] = {a.x, a.y, a.z, a.w};
            float bv[4] = {b.x, b.y, b.z, b.w};
            #pragma unroll
            for (int i = 0; i < 4; i++)
                #pragma unroll
                for (int j = 0; j < 4; j++)
                    acc[i][j] = fmaf(av[i], bv[j], acc[i][j]);
        }
        __syncthreads();
    }
    #pragma unroll
    for (int i = 0; i < 4; i++) {
        int row = m0 + tm * 4 + i;
        int b = row >> 8, rr = row & 255;
        #pragma unroll
        for (int j = 0; j < 4; j++) {
            int col = n0 + tn * 4 + j;
            int s2 = col >> 8, hh = (col >> 5) & 7, d = col & 31;
            float* dst = s2 == 0 ? oq : (s2 == 1 ? ok : ov);
            dst[(((size_t)(b * 8 + hh)) * 256 + rr) * 32 + d] = acc[i][j];
        }
    }
}

// ---------------- mask bit-packing ----------------
__global__ __launch_bounds__(256) void maskpack_kernel(
    const void* __restrict__ mask, unsigned int* __restrict__ maskT,
    const int* __restrict__ flags)
{
    int bh = blockIdx.x >> 7;
    int x0 = (blockIdx.x & 127) * 32;
    int t = threadIdx.x;
    int wv = t >> 6, lane = t & 63;
    int mode = flags[0];
    __shared__ unsigned int lds[32][8];
    for (int it = 0; it < 8; it++) {
        int xl = wv * 8 + it;
        size_t rb = ((size_t)bh * 4096 + x0 + xl) * 256;
        unsigned int nib;
        if (mode == 0) {
            uint4 m = ((const uint4*)((const unsigned int*)mask + rb))[lane];
            nib = (unsigned int)(m.x != 0u) | ((unsigned int)(m.y != 0u) << 1)
                | ((unsigned int)(m.z != 0u) << 2) | ((unsigned int)(m.w != 0u) << 3);
        } else if (mode == 1) {
            unsigned int m = ((const unsigned int*)mask)[rb / 4 + lane];
            nib = (unsigned int)((m & 0xFFu) != 0u) | ((unsigned int)((m & 0xFF00u) != 0u) << 1)
                | ((unsigned int)((m & 0xFF0000u) != 0u) << 2)
                | ((unsigned int)((m & 0xFF000000u) != 0u) << 3);
        } else {
            uint2 m = ((const uint2*)((const unsigned short*)mask + rb))[lane];
            nib = (unsigned int)((m.x & 0xFFFFu) != 0u) | ((unsigned int)((m.x >> 16) != 0u) << 1)
                | ((unsigned int)((m.y & 0xFFFFu) != 0u) << 2)
                | ((unsigned int)((m.y >> 16) != 0u) << 3);
        }
        unsigned long long b0 = __ballot((nib & 1u) != 0u);
        unsigned long long b1 = __ballot((nib & 2u) != 0u);
        unsigned long long b2 = __ballot((nib & 4u) != 0u);
        unsigned long long b3 = __ballot((nib & 8u) != 0u);
        if (lane < 8) {
            int j = lane >> 1;
            unsigned long long bb = j == 0 ? b0 : j == 1 ? b1 : j == 2 ? b2 : b3;
            lds[xl][lane] = (lane & 1) ? (unsigned int)(bb >> 32) : (unsigned int)bb;
        }
    }
    __syncthreads();
    int widx = (t & 3) * 2 + (t >> 7);
    int bitpos = (t >> 2) & 31;
    unsigned int w = 0u;
    #pragma unroll
    for (int xl = 0; xl < 32; xl++)
        w |= ((lds[xl][widx] >> bitpos) & 1u) << xl;
    maskT[((size_t)bh * 256 + t) * 128 + (x0 >> 5)] = w;
}

// ---------------- xkprep: xkT f32 [bh][d][x] -> hi/lo bf16 [bh][x][d] ----------------
// Enables direct, dense-coalesced global B-fragment loads in s1p1 (no per-chunk
// LDS transpose). 16 MB read / 16 MB write, ~5 us.
__global__ __launch_bounds__(256) void xkprep_kernel(
    const float* __restrict__ xkT,
    unsigned short* __restrict__ xkBh, unsigned short* __restrict__ xkBl)
{
    __shared__ __align__(16) float T[32][132];
    int bh = blockIdx.y, x0 = blockIdx.x * 128;
    int t = threadIdx.x;
    {
        int d = t >> 3, xo = (t & 7) * 16;
        const float* src = &xkT[((size_t)bh * 32 + d) * 4096 + x0 + xo];
        float4 a0 = *(const float4*)&src[0];
        float4 a1 = *(const float4*)&src[4];
        float4 a2 = *(const float4*)&src[8];
        float4 a3 = *(const float4*)&src[12];
        *(float4*)&T[d][xo + 0]  = a0;
        *(float4*)&T[d][xo + 4]  = a1;
        *(float4*)&T[d][xo + 8]  = a2;
        *(float4*)&T[d][xo + 12] = a3;
    }
    __syncthreads();
    {
        int x = t >> 1, hf = (t & 1) * 16;
        unsigned int hw[8], lw[8];
        #pragma unroll
        for (int i = 0; i < 8; i++) {
            float v0 = T[hf + 2 * i][x];
            float v1 = T[hf + 2 * i + 1][x];
            unsigned short h0 = f2b(v0), h1 = f2b(v1);
            hw[i] = (unsigned int)h0 | ((unsigned int)h1 << 16);
            lw[i] = (unsigned int)f2b(v0 - b2f(h0))
                  | ((unsigned int)f2b(v1 - b2f(h1)) << 16);
        }
        size_t base = ((size_t)bh * 4096 + x0 + x) * 32 + hf;
        *(uint4*)&xkBh[base]     = make_uint4(hw[0], hw[1], hw[2], hw[3]);
        *(uint4*)&xkBh[base + 8] = make_uint4(hw[4], hw[5], hw[6], hw[7]);
        *(uint4*)&xkBl[base]     = make_uint4(lw[0], lw[1], lw[2], lw[3]);
        *(uint4*)&xkBl[base + 8] = make_uint4(lw[4], lw[5], lw[6], lw[7]);
    }
}

// ---------------- s1p1 fused: S recomputed twice, argmax + softmax, bf16 P ----
// grid (16 ktiles of 16, 32 bh) = 512 blocks (exactly 2/CU), 256 thr = 4 waves;
// wave w covers x in [w*1024, w*1024+1024) in 32 chunks of 32. Pass A and B run
// IDENTICAL split-bf16 MFMA sequences (deterministic; same hh+lh+hl order as the
// verified s1 v2). Pass A: bucket sums of |S| (pre-mask, per polar) + masked row
// max. Pass B: bias + exp(lv - mx) -> UNNORMALIZED bf16 P (bounded by e^maxbias)
// + row sums; 1/sum applied in av1 via isum[]. S f32 never touches HBM.
__global__ __launch_bounds__(256) void s1p1_kernel(
    const float* __restrict__ kq,
    const unsigned short* __restrict__ xkBh, const unsigned short* __restrict__ xkBl,
    const int* __restrict__ rd, const int* __restrict__ polar,
    const unsigned int* __restrict__ maskT,
    const void* __restrict__ dis_emb, const void* __restrict__ polar_emb,
    float* __restrict__ S, int* __restrict__ mori, float* __restrict__ isum,
    const int* __restrict__ flags)
{
    __shared__ __align__(16) unsigned short Ah[16 * 40];
    __shared__ __align__(16) unsigned short Al[16 * 40];
    __shared__ unsigned int mstg[16][128];
    __shared__ float Tb[594];
    __shared__ __align__(16) unsigned short Pst[4][16 * 40];
    __shared__ float redB[4][16][9];
    __shared__ float redM[4][16];
    __shared__ float mxS[16];
    __shared__ int moS[16];
    int bhg = blockIdx.y, b = bhg >> 3, h = bhg & 7;
    int k0 = blockIdx.x * 16;
    int id = threadIdx.x;
    int bf = flags[1];
    int w = id >> 6, l = id & 63, g = l >> 4, kl = l & 15;
    // fused bias table (f32, same math as p1 v4)
    for (int e = id; e < 528; e += 256) {
        int r = e >> 3, j = e & 7;
        float dv = bf ? b2f(((const unsigned short*)dis_emb)[r * 8 + h])
                      : ((const float*)dis_emb)[r * 8 + h];
        float pe = bf ? b2f(((const unsigned short*)polar_emb)[j])
                      : ((const float*)polar_emb)[j];
        Tb[r * 9 + j] = dv + pe;
    }
    // stage kq rows hi/lo (16 k x 32 d)
    if (id < 128) {
        int row = id >> 3, d0 = (id & 7) * 4;
        float4 a4 = *(const float4*)&kq[((size_t)bhg * 256 + k0 + row) * 32 + d0];
        float e[4] = {a4.x, a4.y, a4.z, a4.w};
        #pragma unroll
        for (int j = 0; j < 4; j++) {
            unsigned short h0 = f2b(e[j]);
            Ah[row * 40 + d0 + j] = h0;
            Al[row * 40 + d0 + j] = f2b(e[j] - b2f(h0));
        }
    }
    // stage mask words (16 rows x 128 words)
    for (int i = id; i < 2048; i += 256)
        mstg[i >> 7][i & 127] =
            maskT[((size_t)(bhg * 256 + k0 + (i >> 7))) * 128 + (i & 127)];
    __syncthreads();
    bh8 ah = *(const bh8*)&Ah[kl * 40 + g * 8];
    bh8 al = *(const bh8*)&Al[kl * 40 + g * 8];
    const int* prow_base = &polar[((size_t)(b * 256 + k0)) * 4096];
    // ---- pass A: buckets (pre-mask |S|) + masked row max ----
    float buckets[4][8] = {};
    float mx4[4] = {-3.0e38f, -3.0e38f, -3.0e38f, -3.0e38f};
    for (int it = 0; it < 32; ++it) {
        int xc = w * 1024 + it * 32;
        size_t bb0 = ((size_t)bhg * 4096 + xc + kl) * 32 + g * 8;
        size_t bb1 = ((size_t)bhg * 4096 + xc + 16 + kl) * 32 + g * 8;
        bh8 b0h = *(const bh8*)&xkBh[bb0];
        bh8 b0l = *(const bh8*)&xkBl[bb0];
        bh8 b1h = *(const bh8*)&xkBh[bb1];
        bh8 b1l = *(const bh8*)&xkBl[bb1];
        fx4 z = {0.f, 0.f, 0.f, 0.f};
        fx4 s0 = __builtin_amdgcn_mfma_f32_16x16x32_bf16(ah, b0h, z, 0, 0, 0);
        s0 = __builtin_amdgcn_mfma_f32_16x16x32_bf16(al, b0h, s0, 0, 0, 0);
        s0 = __builtin_amdgcn_mfma_f32_16x16x32_bf16(ah, b0l, s0, 0, 0, 0);
        fx4 s1 = __builtin_amdgcn_mfma_f32_16x16x32_bf16(ah, b1h, z, 0, 0, 0);
        s1 = __builtin_amdgcn_mfma_f32_16x16x32_bf16(al, b1h, s1, 0, 0, 0);
        s1 = __builtin_amdgcn_mfma_f32_16x16x32_bf16(ah, b1l, s1, 0, 0, 0);
        #pragma unroll
        for (int nt = 0; nt < 2; nt++) {
            int x = xc + nt * 16 + kl;
            #pragma unroll
            for (int r = 0; r < 4; r++) {
                int krow = g * 4 + r;
                float sval = (nt == 0 ? s0[r] : s1[r]) * SCALE;
                int pol = prow_base[(size_t)krow * 4096 + x];
                pol = pol < 0 ? 0 : (pol > 7 ? 7 : pol);
                float a = fabsf(sval);
                #pragma unroll
                for (int o = 0; o < 8; o++)
                    buckets[r][o] += (pol == o) ? a : 0.f;
                unsigned int mw = mstg[krow][x >> 5];
                float lv = ((mw >> (x & 31)) & 1u) ? -1e6f : sval;
                mx4[r] = fmaxf(mx4[r], lv);
            }
        }
    }
    // reduce over the 16-lane group (x within wave-range), store per-wave
    #pragma unroll
    for (int r = 0; r < 4; r++) {
        #pragma unroll
        for (int o = 0; o < 8; o++) {
            float v = buckets[r][o];
            v += __shfl_xor(v, 1); v += __shfl_xor(v, 2);
            v += __shfl_xor(v, 4); v += __shfl_xor(v, 8);
            buckets[r][o] = v;
        }
        float m = mx4[r];
        m = fmaxf(m, __shfl_xor(m, 1)); m = fmaxf(m, __shfl_xor(m, 2));
        m = fmaxf(m, __shfl_xor(m, 4)); m = fmaxf(m, __shfl_xor(m, 8));
        mx4[r] = m;
    }
    if (kl == 0) {
        #pragma unroll
        for (int r = 0; r < 4; r++) {
            #pragma unroll
            for (int o = 0; o < 8; o++) redB[w][g * 4 + r][o] = buckets[r][o];
            redM[w][g * 4 + r] = mx4[r];
        }
    }
    __syncthreads();
    if (id < 16) {
        float best = -1.f; int mo = 0;
        #pragma unroll
        for (int o = 0; o < 8; o++) {
            float v = redB[0][id][o] + redB[1][id][o]
                    + redB[2][id][o] + redB[3][id][o];
            if (o == 0 || v > best) { best = v; mo = (o == 0 || v > best) ? o : mo; }
        }
        // (rewrite cleanly to match p1's first-wins semantics)
        best = redB[0][id][0] + redB[1][id][0] + redB[2][id][0] + redB[3][id][0];
        mo = 0;
        #pragma unroll
        for (int o = 1; o < 8; o++) {
            float v = redB[0][id][o] + redB[1][id][o]
                    + redB[2][id][o] + redB[3][id][o];
            if (v > best) { best = v; mo = o; }
        }
        moS[id] = mo;
        mxS[id] = fmaxf(fmaxf(redM[0][id], redM[1][id]),
                        fmaxf(redM[2][id], redM[3][id]));
        mori[bhg * 256 + k0 + id] = mo;
    }
    __syncthreads();
    // ---- pass B: recompute S, bias + exp(lv - mx), write bf16 P + sums ----
    float mxr[4]; int mor[4];
    #pragma unroll
    for (int r = 0; r < 4; r++) { mxr[r] = mxS[g * 4 + r]; mor[r] = moS[g * 4 + r]; }
    float sum4[4] = {};
    unsigned short* Pg = (unsigned short*)S;
    const int* rrow_base = &rd[((size_t)(b * 256 + k0)) * 4096];
    int cpr = l >> 2, cps = l & 3;   // cooperative P write: row, 8-u16 segment
    for (int it = 0; it < 32; ++it) {
        int xc = w * 1024 + it * 32;
        size_t bb0 = ((size_t)bhg * 4096 + xc + kl) * 32 + g * 8;
        size_t bb1 = ((size_t)bhg * 4096 + xc + 16 + kl) * 32 + g * 8;
        bh8 b0h = *(const bh8*)&xkBh[bb0];
        bh8 b0l = *(const bh8*)&xkBl[bb0];
        bh8 b1h = *(const bh8*)&xkBh[bb1];
        bh8 b1l = *(const bh8*)&xkBl[bb1];
        fx4 z = {0.f, 0.f, 0.f, 0.f};
        fx4 s0 = __builtin_amdgcn_mfma_f32_16x16x32_bf16(ah, b0h, z, 0, 0, 0);
        s0 = __builtin_amdgcn_mfma_f32_16x16x32_bf16(al, b0h, s0, 0, 0, 0);
        s0 = __builtin_amdgcn_mfma_f32_16x16x32_bf16(ah, b0l, s0, 0, 0, 0);
        fx4 s1 = __builtin_amdgcn_mfma_f32_16x16x32_bf16(ah, b1h, z, 0, 0, 0);
        s1 = __builtin_amdgcn_mfma_f32_16x16x32_bf16(al, b1h, s1, 0, 0, 0);
        s1 = __builtin_amdgcn_mfma_f32_16x16x32_bf16(ah, b1l, s1, 0, 0, 0);
        #pragma unroll
        for (int nt = 0; nt < 2; nt++) {
            int x = xc + nt * 16 + kl;
            #pragma unroll
            for (int r = 0; r < 4; r++) {
                int krow = g * 4 + r;
                float sval = (nt == 0 ? s0[r] : s1[r]) * SCALE;
                int pol = prow_base[(size_t)krow * 4096 + x];
                pol = pol < 0 ? 0 : (pol > 7 ? 7 : pol);
                int rv = rrow_base[(size_t)krow * 4096 + x];
                unsigned int mw = mstg[krow][x >> 5];
                float lv = ((mw >> (x & 31)) & 1u) ? -1e6f : sval;
                float e = __expf(lv + Tb[rv * 9 + ((pol - mor[r] + 8) & 7)] - mxr[r]);
                sum4[r] += e;
                Pst[w][krow * 40 + nt * 16 + kl] = f2b(e);
            }
        }
        // cooperative 64B-coalesced write of the 16k x 32x chunk (wave-private)
        uint4 pv4 = *(const uint4*)&Pst[w][cpr * 40 + cps * 8];
        *(uint4*)&Pg[((size_t)(bhg * 256 + k0 + cpr)) * 8192 + 4096 + xc + cps * 8] = pv4;
    }
    #pragma unroll
    for (int r = 0; r < 4; r++) {
        float v = sum4[r];
        v += __shfl_xor(v, 1); v += __shfl_xor(v, 2);
        v += __shfl_xor(v, 4); v += __shfl_xor(v, 8);
        if (kl == 0) redM[w][g * 4 + r] = v;
    }
    __syncthreads();
    if (id < 16)
        isum[bhg * 256 + k0 + id] =
            1.f / (redM[0][id] + redM[1][id] + redM[2][id] + redM[3][id]);
}

// ---------------- av1 v4: MFMA P@V on unnormalized P; scale by isum ----------------
__global__ __launch_bounds__(256) void av1_kernel(
    const float* __restrict__ S, const float* __restrict__ xv,
    const float* __restrict__ isum, float* __restrict__ k_att)
{
    __shared__ __align__(16) unsigned short Pa[4][16 * 40];
    __shared__ __align__(16) unsigned short Vt[4][32 * 40];
    __shared__ __align__(16) float red[4][512];
    int bhg = blockIdx.y, b = bhg >> 3, h = bhg & 7;
    int k0 = blockIdx.x * 16;
    int id = threadIdx.x;
    int w = id >> 6, l = id & 63, g = l >> 4, kl = l & 15;
    const unsigned short* Pb = (const unsigned short*)S;
    const float* vb = &xv[(size_t)bhg * 4096 * 32];
    int prl = l >> 2, psg = (l & 3) * 8;
    size_t pbase = ((size_t)(bhg * 256 + k0 + prl)) * 8192 + 4096;
    int vr = l >> 1, vdh = (l & 1) * 16;
    fx4 acc0 = {0.f, 0.f, 0.f, 0.f}, acc1 = {0.f, 0.f, 0.f, 0.f};
    for (int it = 0; it < 32; ++it) {
        int xc = w * 1024 + it * 32;
        uint4 pq = *(const uint4*)&Pb[pbase + xc + psg];
        const float* vp = &vb[(size_t)(xc + vr) * 32 + vdh];
        float4 v0 = *(const float4*)&vp[0];
        float4 v1 = *(const float4*)&vp[4];
        float4 v2 = *(const float4*)&vp[8];
        float4 v3 = *(const float4*)&vp[12];
        *(uint4*)&Pa[w][prl * 40 + psg] = pq;
        float ve[16] = {v0.x, v0.y, v0.z, v0.w, v1.x, v1.y, v1.z, v1.w,
                        v2.x, v2.y, v2.z, v2.w, v3.x, v3.y, v3.z, v3.w};
        #pragma unroll
        for (int i = 0; i < 16; i++)
            Vt[w][(vdh + i) * 40 + vr] = f2b(ve[i]);
        bh8 a  = *(const bh8*)&Pa[w][kl * 40 + g * 8];
        bh8 b0 = *(const bh8*)&Vt[w][kl * 40 + g * 8];
        bh8 b1 = *(const bh8*)&Vt[w][(16 + kl) * 40 + g * 8];
        acc0 = __builtin_amdgcn_mfma_f32_16x16x32_bf16(a, b0, acc0, 0, 0, 0);
        acc1 = __builtin_amdgcn_mfma_f32_16x16x32_bf16(a, b1, acc1, 0, 0, 0);
    }
    #pragma unroll
    for (int r = 0; r < 4; r++) {
        red[w][(g * 4 + r) * 32 + kl]      = acc0[r];
        red[w][(g * 4 + r) * 32 + 16 + kl] = acc1[r];
    }
    __syncthreads();
    #pragma unroll
    for (int rep = 0; rep < 2; rep++) {
        int e = rep * 256 + id;
        float s = red[0][e] + red[1][e] + red[2][e] + red[3][e];
        int kk_ = e >> 5, dd = e & 31;
        float sc = isum[(size_t)bhg * 256 + k0 + kk_];
        k_att[((size_t)(b * 256 + k0 + kk_)) * 256 + h * 32 + dd] = s * sc;
    }
}

// ---------------- fa2 v5: MFMA flash attention (16x16x32 bf16) ----------------
__global__ __launch_bounds__(256) void fa2_kernel(
    const float* __restrict__ kkM, const float* __restrict__ xqT, const float* __restrict__ kvM,
    const int* __restrict__ rd, const int* __restrict__ polar,
    const unsigned int* __restrict__ maskT,
    const void* __restrict__ dis_emb, const void* __restrict__ polar_emb,
    const int* __restrict__ mori, const int* __restrict__ flags,
    float* __restrict__ x_att)
{
    __shared__ __align__(16) unsigned short Qs[128 * 40];
    __shared__ __align__(16) unsigned short Ks[32 * 40];
    __shared__ __align__(16) unsigned short VtT[32 * 40];
    __shared__ __align__(16) unsigned short Pt[4][32 * 40];
    __shared__ __align__(16) unsigned short rp[32 * 136];
    __shared__ unsigned short Tb[528];
    __shared__ unsigned int mstg[32][4];
    __shared__ unsigned char mo_l[256];
    int bhg = blockIdx.y, b = bhg >> 3, h = bhg & 7;
    int x0 = blockIdx.x * 128;
    int id = threadIdx.x;
    int bf = flags[1];
    int w = id >> 6, l = id & 63, g = l >> 4, kl = l & 15;
    for (int e = id; e < 528; e += 256) {
        int r = e >> 3, j = e & 7;
        float dv = bf ? b2f(((const unsigned short*)dis_emb)[r * 8 + h])
                      : ((const float*)dis_emb)[r * 8 + h];
        float pe = bf ? b2f(((const unsigned short*)polar_emb)[j])
                      : ((const float*)polar_emb)[j];
        Tb[e] = f2b(dv + pe);
    }
    mo_l[id] = (unsigned char)mori[(size_t)bhg * 256 + id];
    #pragma unroll
    for (int rep = 0; rep < 4; rep++) {
        int idx = rep * 256 + id;
        int d = idx >> 5, c = (idx & 31) * 4;
        float4 q4 = *(const float4*)&xqT[((size_t)bhg * 32 + d) * 4096 + x0 + c];
        Qs[(c + 0) * 40 + d] = f2b(q4.x);
        Qs[(c + 1) * 40 + d] = f2b(q4.y);
        Qs[(c + 2) * 40 + d] = f2b(q4.z);
        Qs[(c + 3) * 40 + d] = f2b(q4.w);
    }
    fx4 o00 = {0.f, 0.f, 0.f, 0.f}, o01 = {0.f, 0.f, 0.f, 0.f};
    fx4 o10 = {0.f, 0.f, 0.f, 0.f}, o11 = {0.f, 0.f, 0.f, 0.f};
    float mrow[2][4], lrow[2][4];
    #pragma unroll
    for (int s = 0; s < 2; s++)
        #pragma unroll
        for (int r = 0; r < 4; r++) { mrow[s][r] = -3.0e38f; lrow[s][r] = 0.f; }
    __syncthreads();
    for (int kc = 0; kc < 256; kc += 32) {
        {
            int k = id >> 3, d0 = (id & 7) * 4;
            float4 k4 = *(const float4*)&kkM[((size_t)bhg * 256 + kc + k) * 32 + d0];
            *(unsigned int*)&Ks[k * 40 + d0] =
                (unsigned int)f2b(k4.x) | ((unsigned int)f2b(k4.y) << 16);
            *(unsigned int*)&Ks[k * 40 + d0 + 2] =
                (unsigned int)f2b(k4.z) | ((unsigned int)f2b(k4.w) << 16);
            float4 v4 = *(const float4*)&kvM[((size_t)bhg * 256 + kc + k) * 32 + d0];
            VtT[(d0 + 0) * 40 + k] = f2b(v4.x);
            VtT[(d0 + 1) * 40 + k] = f2b(v4.y);
            VtT[(d0 + 2) * 40 + k] = f2b(v4.z);
            VtT[(d0 + 3) * 40 + k] = f2b(v4.w);
            if (id < 128)
                mstg[id >> 2][id & 3] =
                    maskT[((size_t)bhg * 256 + kc + (id >> 2)) * 128 + (x0 >> 5) + (id & 3)];
        }
        {
            int k = id >> 3, xb = (id & 7) * 16;
            size_t rib = ((size_t)b * 256 + kc + k) * 4096 + x0 + xb;
            __align__(16) unsigned short tmp[16];
            #pragma unroll
            for (int q = 0; q < 4; q++) {
                int4 rv = *(const int4*)&rd[rib + q * 4];
                int4 pq = *(const int4*)&polar[rib + q * 4];
                int pa = pq.x < 0 ? 0 : (pq.x > 7 ? 7 : pq.x);
                int pb = pq.y < 0 ? 0 : (pq.y > 7 ? 7 : pq.y);
                int pc = pq.z < 0 ? 0 : (pq.z > 7 ? 7 : pq.z);
                int pd = pq.w < 0 ? 0 : (pq.w > 7 ? 7 : pq.w);
                tmp[q * 4 + 0] = (unsigned short)(rv.x | (pa << 8));
                tmp[q * 4 + 1] = (unsigned short)(rv.y | (pb << 8));
                tmp[q * 4 + 2] = (unsigned short)(rv.z | (pc << 8));
                tmp[q * 4 + 3] = (unsigned short)(rv.w | (pd << 8));
            }
            *(uint4*)&rp[k * 136 + xb]     = *(const uint4*)&tmp[0];
            *(uint4*)&rp[k * 136 + xb + 8] = *(const uint4*)&tmp[8];
        }
        __syncthreads();
        bh8 aq0 = *(const bh8*)&Qs[(w * 32 + kl) * 40 + g * 8];
        bh8 aq1 = *(const bh8*)&Qs[(w * 32 + 16 + kl) * 40 + g * 8];
        bh8 bk0 = *(const bh8*)&Ks[kl * 40 + g * 8];
        bh8 bk1 = *(const bh8*)&Ks[(16 + kl) * 40 + g * 8];
        fx4 z = {0.f, 0.f, 0.f, 0.f};
        fx4 s00 = __builtin_amdgcn_mfma_f32_16x16x32_bf16(aq0, bk0, z, 0, 0, 0);
        fx4 s01 = __builtin_amdgcn_mfma_f32_16x16x32_bf16(aq0, bk1, z, 0, 0, 0);
        fx4 s10 = __builtin_amdgcn_mfma_f32_16x16x32_bf16(aq1, bk0, z, 0, 0, 0);
        fx4 s11 = __builtin_amdgcn_mfma_f32_16x16x32_bf16(aq1, bk1, z, 0, 0, 0);
        float vv[2][2][4];
        #pragma unroll
        for (int j = 0; j < 2; j++) {
            int k_loc = j * 16 + kl;
            int mo = mo_l[kc + k_loc];
            unsigned int mw = mstg[k_loc][w];
            #pragma unroll
            for (int s = 0; s < 2; s++) {
                #pragma unroll
                for (int r = 0; r < 4; r++) {
                    int bit = s * 16 + g * 4 + r;
                    unsigned short rpv = rp[k_loc * 136 + w * 32 + bit];
                    float bias = b2f(Tb[(rpv & 0xFF) * 8 + ((((int)(rpv >> 8)) - mo + 8) & 7)]);
                    float sc = (s == 0) ? (j == 0 ? s00[r] : s01[r])
                                        : (j == 0 ? s10[r] : s11[r]);
                    vv[s][j][r] = (((mw >> bit) & 1u) ? -1e9f : sc * SCALE) + bias;
                }
            }
        }
        float frs[2][4];
        #pragma unroll
        for (int s = 0; s < 2; s++) {
            #pragma unroll
            for (int r = 0; r < 4; r++) {
                float pm = fmaxf(vv[s][0][r], vv[s][1][r]);
                pm = fmaxf(pm, __shfl_xor(pm, 1));
                pm = fmaxf(pm, __shfl_xor(pm, 2));
                pm = fmaxf(pm, __shfl_xor(pm, 4));
                pm = fmaxf(pm, __shfl_xor(pm, 8));
                float mn = fmaxf(mrow[s][r], pm);
                float e0 = __expf(vv[s][0][r] - mn);
                float e1 = __expf(vv[s][1][r] - mn);
                float cs = e0 + e1;
                cs += __shfl_xor(cs, 1);
                cs += __shfl_xor(cs, 2);
                cs += __shfl_xor(cs, 4);
                cs += __shfl_xor(cs, 8);
                float f = __expf(mrow[s][r] - mn);
                mrow[s][r] = mn;
                lrow[s][r] = lrow[s][r] * f + cs;
                frs[s][r] = f;
                vv[s][0][r] = e0;
                vv[s][1][r] = e1;
            }
        }
        #pragma unroll
        for (int s = 0; s < 2; s++)
            #pragma unroll
            for (int j = 0; j < 2; j++)
                #pragma unroll
                for (int r = 0; r < 4; r++)
                    Pt[w][(s * 16 + g * 4 + r) * 40 + j * 16 + kl] = f2b(vv[s][j][r]);
        #pragma unroll
        for (int r = 0; r < 4; r++) {
            o00[r] *= frs[0][r]; o01[r] *= frs[0][r];
            o10[r] *= frs[1][r]; o11[r] *= frs[1][r];
        }
        bh8 pa0 = *(const bh8*)&Pt[w][kl * 40 + g * 8];
        bh8 pa1 = *(const bh8*)&Pt[w][(16 + kl) * 40 + g * 8];
        bh8 bv0 = *(const bh8*)&VtT[kl * 40 + g * 8];
        bh8 bv1 = *(const bh8*)&VtT[(16 + kl) * 40 + g * 8];
        o00 = __builtin_amdgcn_mfma_f32_16x16x32_bf16(pa0, bv0, o00, 0, 0, 0);
        o01 = __builtin_amdgcn_mfma_f32_16x16x32_bf16(pa0, bv1, o01, 0, 0, 0);
        o10 = __builtin_amdgcn_mfma_f32_16x16x32_bf16(pa1, bv0, o10, 0, 0, 0);
        o11 = __builtin_amdgcn_mfma_f32_16x16x32_bf16(pa1, bv1, o11, 0, 0, 0);
        __syncthreads();
    }
    #pragma unroll
    for (int s = 0; s < 2; s++) {
        #pragma unroll
        for (int r = 0; r < 4; r++) {
            float inv = 1.f / lrow[s][r];
            int x = x0 + w * 32 + s * 16 + g * 4 + r;
            size_t ob = ((size_t)b * 4096 + x) * 256 + h * 32;
            x_att[ob + kl]      = (s == 0 ? o00[r] : o10[r]) * inv;
            x_att[ob + 16 + kl] = (s == 0 ? o01[r] : o11[r]) * inv;
        }
    }
}

// ---------------- final projection ----------------
__global__ __launch_bounds__(256) void proj_kernel(
    const float* __restrict__ A, const void* __restrict__ W, const void* __restrict__ bias,
    float* __restrict__ out, const int* __restrict__ flags)
{
    __shared__ __align__(16) float As[16][68];
    __shared__ __align__(16) float Bs[16][64];
    int bf = flags[1];
    const float* W32 = (const float*)W;
    const unsigned short* W16 = (const unsigned short*)W;
    int m0 = blockIdx.x * 64, n0 = blockIdx.y * 64;
    int id = threadIdx.x, tm = id >> 4, tn = id & 15;
    float acc[4][4] = {};
    for (int k0 = 0; k0 < 256; k0 += 16) {
        int rr = id >> 2, ck = (id & 3) * 4;
        int rk = id >> 4, cn = (id & 15) * 4;
        {
            float4 a4 = *(const float4*)&A[(size_t)(m0 + rr) * 256 + k0 + ck];
            As[ck + 0][rr] = a4.x; As[ck + 1][rr] = a4.y;
            As[ck + 2][rr] = a4.z; As[ck + 3][rr] = a4.w;
        }
        if (bf) {
            uint2 w2 = *(const uint2*)&W16[(size_t)(k0 + rk) * 256 + n0 + cn];
            Bs[rk][cn + 0] = b2f(w2.x & 0xFFFFu); Bs[rk][cn + 1] = b2f(w2.x >> 16);
            Bs[rk][cn + 2] = b2f(w2.y & 0xFFFFu); Bs[rk][cn + 3] = b2f(w2.y >> 16);
        } else {
            *(float4*)&Bs[rk][cn] = *(const float4*)&W32[(size_t)(k0 + rk) * 256 + n0 + cn];
        }
        __syncthreads();
        #pragma unroll
        for (int kk = 0; kk < 16; kk++) {
            float4 a = *(const float4*)&As[kk][tm * 4];
            float4 b = *(const float4*)&Bs[kk][tn * 4];
            float av[4] = {a.x, a.y, a.z, a.w};
            float bv[4] = {b.x, b.y, b.z, b.w};
            #pragma unroll
            for (int i = 0; i < 4; i++)
                #pragma unroll
                for (int j = 0; j < 4; j++)
                    acc[i][j] = fmaf(av[i], bv[j], acc[i][j]);
        }
        __syncthreads();
    }
    #pragma unroll
    for (int i = 0; i < 4; i++) {
        int col = n0 + tn * 4;
        float b0 = bf ? b2f(((const unsigned short*)bias)[col + 0]) : ((const float*)bias)[col + 0];
        float b1 = bf ? b2f(((const unsigned short*)bias)[col + 1]) : ((const float*)bias)[col + 1];
        float b2v = bf ? b2f(((const unsigned short*)bias)[col + 2]) : ((const float*)bias)[col + 2];
        float b3 = bf ? b2f(((const unsigned short*)bias)[col + 3]) : ((const float*)bias)[col + 3];
        float4 o = make_float4(acc[i][0] + b0, acc[i][1] + b1, acc[i][2] + b2v, acc[i][3] + b3);
        *(float4*)&out[(size_t)(m0 + tm * 4 + i) * 256 + col] = o;
    }
}

extern "C" void kernel_launch(void* const* d_in, const int* in_sizes, int n_in,
                              void* d_out, int out_size, void* d_ws, size_t ws_size,
                              hipStream_t stream) {
    (void)in_sizes; (void)n_in; (void)out_size; (void)ws_size;
    const void* x         = d_in[0];
    const void* kern      = d_in[1];
    const int*  rd        = (const int*)d_in[2];
    const int*  polar     = (const int*)d_in[3];
    const void* amask     = d_in[4];
    const void* w_qkv     = d_in[5];
    const void* w_proj    = d_in[6];
    const void* b_proj    = d_in[7];
    const void* polar_emb = d_in[8];
    const void* dis_emb   = d_in[9];
    float* out = (float*)d_out;

    float* ws = (float*)d_ws;
    float* S     = ws + OFF_S;
    float* xqT   = ws + OFF_XQT;
    float* xv    = ws + OFF_XV;
    float* xkT   = ws + OFF_XKT;
    float* kq    = ws + OFF_KQ;
    float* kkM   = ws + OFF_KK;
    float* kvM   = ws + OFF_KV;
    float* k_att = ws + OFF_KATT;
    float* x_att = ws + OFF_XATT;
    unsigned int* maskT = (unsigned int*)(ws + OFF_MT);
    int* mori  = (int*)(ws + OFF_MORI);
    int* flags = (int*)(ws + OFF_FLAG);
    float* isum = ws + OFF_ISUM;
    unsigned short* xkBh = (unsigned short*)(ws + OFF_XKBH);
    unsigned short* xkBl = (unsigned short*)(ws + OFF_XKBL);

    detect_kernel<<<2, 256, 0, stream>>>((const unsigned int*)amask, (const unsigned int*)x, flags);
    qkv128_kernel<<<dim3(128, 12), 256, 0, stream>>>(x, w_qkv, xqT, xkT, xv, flags);
    qkv_kernel<<<dim3(16, 12), 256, 0, stream>>>(kern, w_qkv, kq, kkM, kvM, flags);
    maskpack_kernel<<<4096, 256, 0, stream>>>(amask, maskT, flags);
    xkprep_kernel<<<dim3(32, 32), 256, 0, stream>>>(xkT, xkBh, xkBl);

    // FULL-batch pipeline (s1+p1 fused; S f32 never round-trips HBM)
    s1p1_kernel<<<dim3(16, 32), 256, 0, stream>>>(kq, xkBh, xkBl, rd, polar, maskT,
                                                  dis_emb, polar_emb, S, mori, isum, flags);
    av1_kernel<<<dim3(16, 32), 256, 0, stream>>>(S, xv, isum, k_att);
    fa2_kernel<<<dim3(32, 32), 256, 0, stream>>>(kkM, xqT, kvM, rd, polar, maskT,
                                                 dis_emb, polar_emb, mori, flags, x_att);

    proj_kernel<<<dim3(256, 4), 256, 0, stream>>>(x_att, w_proj, b_proj, out, flags);
    proj_kernel<<<dim3(16, 4), 256, 0, stream>>>(k_att, w_proj, b_proj, out + 4194304, flags);
}

// Round 12
// 534.626 us; speedup vs baseline: 1.3023x; 1.3023x over previous
//
#include <hip/hip_runtime.h>
#include <hip/hip_bf16.h>

#define SCALE 0.17677669529663689f  // 32^-0.5

// ---------------- workspace offsets (in floats), total ~210 MB ----------------
#define OFF_S    0UL          // 33,554,432 (FULL batch: 32 bh x 256 k x 4096 x)
#define OFF_XQT  33554432UL   // 4,194,304
#define OFF_XV   37748736UL   // 4,194,304
#define OFF_XKT  41943040UL   // 4,194,304
#define OFF_KQ   46137344UL   // 262,144
#define OFF_KK   46399488UL   // 262,144
#define OFF_KV   46661632UL   // 262,144
#define OFF_KATT 46923776UL   // 262,144
#define OFF_XATT 47185920UL   // 4,194,304
#define OFF_MT   51380224UL   // maskT 4 MB
#define OFF_MORI 52428800UL   // 8192 ints
#define OFF_FLAG 52436992UL

__device__ __forceinline__ float b2f(unsigned int u) {
    union { unsigned int i; float f; } v; v.i = u << 16; return v.f;
}
__device__ __forceinline__ unsigned short f2b(float f) {
    __hip_bfloat16 h = __float2bfloat16(f);
    return *(unsigned short*)&h;
}

typedef short bh8 __attribute__((ext_vector_type(8)));   // 8 bf16 (4 VGPR) MFMA frag
typedef float fx4 __attribute__((ext_vector_type(4)));   // 4 f32 MFMA accum

// ---------------- dtype detection ----------------
__global__ __launch_bounds__(256) void detect_kernel(
    const unsigned int* __restrict__ mask, const unsigned int* __restrict__ xf,
    int* __restrict__ flags)
{
    __shared__ unsigned int orv;
    __shared__ int cnt;
    int t = threadIdx.x;
    if (t == 0) { orv = 0u; cnt = 0; }
    __syncthreads();
    if (blockIdx.x == 0) {
        unsigned int v = 0;
        for (int i = t; i < 16384; i += 256) v |= mask[i];
        atomicOr(&orv, v);
        __syncthreads();
        if (t == 0) {
            unsigned int o = orv;
            int f;
            if (o <= 1u || o == 0x3F800000u) f = 0;
            else if (o & 0x00800080u)        f = 2;
            else                             f = 1;
            flags[0] = f;
        }
    } else {
        int c = 0;
        for (int i = t; i < 4096; i += 256) {
            unsigned int h = xf[i] & 0xFFFFu;
            unsigned int e = (h >> 7) & 0xFFu;
            if (h == 0u || (e >= 0x75u && e <= 0x82u)) c++;
        }
        atomicAdd(&cnt, c);
        __syncthreads();
        if (t == 0) flags[1] = (cnt > 3000) ? 1 : 0;
    }
}

// ---------------- qkv128 v2: MFMA GEMM 128x64, split-bf16 precision ----------------
__global__ __launch_bounds__(256) void qkv128_kernel(
    const void* __restrict__ A, const void* __restrict__ W,
    float* __restrict__ oq, float* __restrict__ ok, float* __restrict__ ov,
    const int* __restrict__ flags)
{
    __shared__ __align__(16) unsigned short Ah[128 * 40];
    __shared__ __align__(16) unsigned short Al[128 * 40];
    __shared__ __align__(16) unsigned short Wh[64 * 40];
    __shared__ __align__(16) unsigned short Wl[64 * 40];
    int bf = flags[1];
    const float* A32 = (const float*)A;
    const float* W32 = (const float*)W;
    const unsigned short* A16 = (const unsigned short*)A;
    const unsigned short* W16 = (const unsigned short*)W;
    int m0 = blockIdx.x * 128;
    int n0 = blockIdx.y * 64;
    int sec = n0 >> 8;  // 0=q, 1=k (argmax path), 2=v
    int id = threadIdx.x;
    int w = id >> 6, l = id & 63, g = l >> 4, kl = l & 15;
    fx4 acc[2][4] = {};
    for (int kc = 0; kc < 256; kc += 32) {
        {
            int r = id >> 1, c0 = (id & 1) * 16;
            if (bf) {
                uint4 p0 = *(const uint4*)&A16[(size_t)(m0 + r) * 256 + kc + c0];
                uint4 p1 = *(const uint4*)&A16[(size_t)(m0 + r) * 256 + kc + c0 + 8];
                *(uint4*)&Ah[r * 40 + c0]     = p0;
                *(uint4*)&Ah[r * 40 + c0 + 8] = p1;
                uint4 z = make_uint4(0u, 0u, 0u, 0u);
                *(uint4*)&Al[r * 40 + c0]     = z;
                *(uint4*)&Al[r * 40 + c0 + 8] = z;
            } else {
                const float* ap = &A32[(size_t)(m0 + r) * 256 + kc + c0];
                float4 f0 = *(const float4*)&ap[0];
                float4 f1 = *(const float4*)&ap[4];
                float4 f2v = *(const float4*)&ap[8];
                float4 f3 = *(const float4*)&ap[12];
                float av[16] = {f0.x, f0.y, f0.z, f0.w, f1.x, f1.y, f1.z, f1.w,
                                f2v.x, f2v.y, f2v.z, f2v.w, f3.x, f3.y, f3.z, f3.w};
                unsigned int hw[8], lw[8];
                #pragma unroll
                for (int j = 0; j < 8; j++) {
                    unsigned short h0 = f2b(av[2 * j]), h1 = f2b(av[2 * j + 1]);
                    hw[j] = (unsigned int)h0 | ((unsigned int)h1 << 16);
                    unsigned short q0 = f2b(av[2 * j] - b2f(h0));
                    unsigned short q1 = f2b(av[2 * j + 1] - b2f(h1));
                    lw[j] = (unsigned int)q0 | ((unsigned int)q1 << 16);
                }
                *(uint4*)&Ah[r * 40 + c0]     = make_uint4(hw[0], hw[1], hw[2], hw[3]);
                *(uint4*)&Ah[r * 40 + c0 + 8] = make_uint4(hw[4], hw[5], hw[6], hw[7]);
                *(uint4*)&Al[r * 40 + c0]     = make_uint4(lw[0], lw[1], lw[2], lw[3]);
                *(uint4*)&Al[r * 40 + c0 + 8] = make_uint4(lw[4], lw[5], lw[6], lw[7]);
            }
        }
        {
            int kp = (id >> 4) * 2, c0w = (id & 15) * 4;
            if (bf) {
                uint2 r0 = *(const uint2*)&W16[(size_t)(kc + kp) * 768 + n0 + c0w];
                uint2 r1 = *(const uint2*)&W16[(size_t)(kc + kp + 1) * 768 + n0 + c0w];
                unsigned int e0[4] = {r0.x & 0xFFFFu, r0.x >> 16, r0.y & 0xFFFFu, r0.y >> 16};
                unsigned int e1[4] = {r1.x & 0xFFFFu, r1.x >> 16, r1.y & 0xFFFFu, r1.y >> 16};
                #pragma unroll
                for (int j = 0; j < 4; j++) {
                    *(unsigned int*)&Wh[(c0w + j) * 40 + kp] = e0[j] | (e1[j] << 16);
                    *(unsigned int*)&Wl[(c0w + j) * 40 + kp] = 0u;
                }
            } else {
                float4 w0 = *(const float4*)&W32[(size_t)(kc + kp) * 768 + n0 + c0w];
                float4 w1 = *(const float4*)&W32[(size_t)(kc + kp + 1) * 768 + n0 + c0w];
                float e0[4] = {w0.x, w0.y, w0.z, w0.w};
                float e1[4] = {w1.x, w1.y, w1.z, w1.w};
                #pragma unroll
                for (int j = 0; j < 4; j++) {
                    unsigned short h0 = f2b(e0[j]), h1 = f2b(e1[j]);
                    *(unsigned int*)&Wh[(c0w + j) * 40 + kp] =
                        (unsigned int)h0 | ((unsigned int)h1 << 16);
                    unsigned short q0 = f2b(e0[j] - b2f(h0));
                    unsigned short q1 = f2b(e1[j] - b2f(h1));
                    *(unsigned int*)&Wl[(c0w + j) * 40 + kp] =
                        (unsigned int)q0 | ((unsigned int)q1 << 16);
                }
            }
        }
        __syncthreads();
        bh8 a0h = *(const bh8*)&Ah[(w * 32 + kl) * 40 + g * 8];
        bh8 a1h = *(const bh8*)&Ah[(w * 32 + 16 + kl) * 40 + g * 8];
        if (sec == 1) {
            bh8 a0l = *(const bh8*)&Al[(w * 32 + kl) * 40 + g * 8];
            bh8 a1l = *(const bh8*)&Al[(w * 32 + 16 + kl) * 40 + g * 8];
            #pragma unroll
            for (int nt = 0; nt < 4; nt++) {
                bh8 bhf = *(const bh8*)&Wh[(nt * 16 + kl) * 40 + g * 8];
                bh8 blf = *(const bh8*)&Wl[(nt * 16 + kl) * 40 + g * 8];
                acc[0][nt] = __builtin_amdgcn_mfma_f32_16x16x32_bf16(a0h, bhf, acc[0][nt], 0, 0, 0);
                acc[0][nt] = __builtin_amdgcn_mfma_f32_16x16x32_bf16(a0l, bhf, acc[0][nt], 0, 0, 0);
                acc[0][nt] = __builtin_amdgcn_mfma_f32_16x16x32_bf16(a0h, blf, acc[0][nt], 0, 0, 0);
                acc[1][nt] = __builtin_amdgcn_mfma_f32_16x16x32_bf16(a1h, bhf, acc[1][nt], 0, 0, 0);
                acc[1][nt] = __builtin_amdgcn_mfma_f32_16x16x32_bf16(a1l, bhf, acc[1][nt], 0, 0, 0);
                acc[1][nt] = __builtin_amdgcn_mfma_f32_16x16x32_bf16(a1h, blf, acc[1][nt], 0, 0, 0);
            }
        } else {
            #pragma unroll
            for (int nt = 0; nt < 4; nt++) {
                bh8 bhf = *(const bh8*)&Wh[(nt * 16 + kl) * 40 + g * 8];
                acc[0][nt] = __builtin_amdgcn_mfma_f32_16x16x32_bf16(a0h, bhf, acc[0][nt], 0, 0, 0);
                acc[1][nt] = __builtin_amdgcn_mfma_f32_16x16x32_bf16(a1h, bhf, acc[1][nt], 0, 0, 0);
            }
        }
        __syncthreads();
    }
    int b = m0 >> 12;
    if (sec < 2) {
        float* dstb = (sec == 0) ? oq : ok;
        #pragma unroll
        for (int mt = 0; mt < 2; mt++) {
            int rr0 = (m0 & 4095) + w * 32 + mt * 16 + g * 4;
            #pragma unroll
            for (int nt = 0; nt < 4; nt++) {
                int col = n0 + nt * 16 + kl;
                int hh = (col >> 5) & 7, d = col & 31;
                *(float4*)&dstb[((size_t)(b * 8 + hh) * 32 + d) * 4096 + rr0] =
                    make_float4(acc[mt][nt][0], acc[mt][nt][1], acc[mt][nt][2], acc[mt][nt][3]);
            }
        }
    } else {
        #pragma unroll
        for (int mt = 0; mt < 2; mt++) {
            int rr0 = (m0 & 4095) + w * 32 + mt * 16 + g * 4;
            #pragma unroll
            for (int nt = 0; nt < 4; nt++) {
                int col = n0 + nt * 16 + kl;
                int hh = (col >> 5) & 7, d0 = col & 31;
                size_t base = ((size_t)(b * 8 + hh) * 4096 + rr0) * 32 + d0;
                ov[base]      = acc[mt][nt][0];
                ov[base + 32] = acc[mt][nt][1];
                ov[base + 64] = acc[mt][nt][2];
                ov[base + 96] = acc[mt][nt][3];
            }
        }
    }
}

// ---------------- qkv (mode-1, kernal): 64x64 tile ----------------
__global__ __launch_bounds__(256) void qkv_kernel(
    const void* __restrict__ A, const void* __restrict__ W,
    float* __restrict__ oq, float* __restrict__ ok, float* __restrict__ ov,
    const int* __restrict__ flags)
{
    __shared__ __align__(16) float As[16][68];
    __shared__ __align__(16) float Bs[16][64];
    int bf = flags[1];
    const float* A32 = (const float*)A;
    const float* W32 = (const float*)W;
    const unsigned short* A16 = (const unsigned short*)A;
    const unsigned short* W16 = (const unsigned short*)W;
    int m0 = blockIdx.x * 64;
    int n0 = blockIdx.y * 64;
    int id = threadIdx.x;
    int tm = id >> 4, tn = id & 15;
    float acc[4][4] = {};
    for (int k0 = 0; k0 < 256; k0 += 16) {
        int r = id >> 2, ck = (id & 3) * 4;
        int rk = id >> 4, cn = (id & 15) * 4;
        if (bf) {
            uint2 a2 = *(const uint2*)&A16[(size_t)(m0 + r) * 256 + k0 + ck];
            As[ck + 0][r] = b2f(a2.x & 0xFFFFu); As[ck + 1][r] = b2f(a2.x >> 16);
            As[ck + 2][r] = b2f(a2.y & 0xFFFFu); As[ck + 3][r] = b2f(a2.y >> 16);
            uint2 w2 = *(const uint2*)&W16[(size_t)(k0 + rk) * 768 + n0 + cn];
            Bs[rk][cn + 0] = b2f(w2.x & 0xFFFFu); Bs[rk][cn + 1] = b2f(w2.x >> 16);
            Bs[rk][cn + 2] = b2f(w2.y & 0xFFFFu); Bs[rk][cn + 3] = b2f(w2.y >> 16);
        } else {
            float4 a4 = *(const float4*)&A32[(size_t)(m0 + r) * 256 + k0 + ck];
            As[ck + 0][r] = a4.x; As[ck + 1][r] = a4.y;
            As[ck + 2][r] = a4.z; As[ck + 3][r] = a4.w;
            *(float4*)&Bs[rk][cn] = *(const float4*)&W32[(size_t)(k0 + rk) * 768 + n0 + cn];
        }
        __syncthreads();
        #pragma unroll
        for (int kk = 0; kk < 16; kk++) {
            float4 a = *(const float4*)&As[kk][tm * 4];
            float4 b = *(const float4*)&Bs[kk][tn * 4];
            float av[4] = {a.x, a.y, a.z, a.w};
            float bv[4] = {b.x, b.y, b.z, b.w};
            #pragma unroll
            for (int i = 0; i < 4; i++)
                #pragma unroll
                for (int j = 0; j < 4; j++)
                    acc[i][j] = fmaf(av[i], bv[j], acc[i][j]);
        }
        __syncthreads();
    }
    #pragma unroll
    for (int i = 0; i < 4; i++) {
        int row = m0 + tm * 4 + i;
        int b = row >> 8, rr = row & 255;
        #pragma unroll
        for (int j = 0; j < 4; j++) {
            int col = n0 + tn * 4 + j;
            int s2 = col >> 8, hh = (col >> 5) & 7, d = col & 31;
            float* dst = s2 == 0 ? oq : (s2 == 1 ? ok : ov);
            dst[(((size_t)(b * 8 + hh)) * 256 + rr) * 32 + d] = acc[i][j];
        }
    }
}

// ---------------- mask bit-packing ----------------
__global__ __launch_bounds__(256) void maskpack_kernel(
    const void* __restrict__ mask, unsigned int* __restrict__ maskT,
    const int* __restrict__ flags)
{
    int bh = blockIdx.x >> 7;
    int x0 = (blockIdx.x & 127) * 32;
    int t = threadIdx.x;
    int wv = t >> 6, lane = t & 63;
    int mode = flags[0];
    __shared__ unsigned int lds[32][8];
    for (int it = 0; it < 8; it++) {
        int xl = wv * 8 + it;
        size_t rb = ((size_t)bh * 4096 + x0 + xl) * 256;
        unsigned int nib;
        if (mode == 0) {
            uint4 m = ((const uint4*)((const unsigned int*)mask + rb))[lane];
            nib = (unsigned int)(m.x != 0u) | ((unsigned int)(m.y != 0u) << 1)
                | ((unsigned int)(m.z != 0u) << 2) | ((unsigned int)(m.w != 0u) << 3);
        } else if (mode == 1) {
            unsigned int m = ((const unsigned int*)mask)[rb / 4 + lane];
            nib = (unsigned int)((m & 0xFFu) != 0u) | ((unsigned int)((m & 0xFF00u) != 0u) << 1)
                | ((unsigned int)((m & 0xFF0000u) != 0u) << 2)
                | ((unsigned int)((m & 0xFF000000u) != 0u) << 3);
        } else {
            uint2 m = ((const uint2*)((const unsigned short*)mask + rb))[lane];
            nib = (unsigned int)((m.x & 0xFFFFu) != 0u) | ((unsigned int)((m.x >> 16) != 0u) << 1)
                | ((unsigned int)((m.y & 0xFFFFu) != 0u) << 2)
                | ((unsigned int)((m.y >> 16) != 0u) << 3);
        }
        unsigned long long b0 = __ballot((nib & 1u) != 0u);
        unsigned long long b1 = __ballot((nib & 2u) != 0u);
        unsigned long long b2 = __ballot((nib & 4u) != 0u);
        unsigned long long b3 = __ballot((nib & 8u) != 0u);
        if (lane < 8) {
            int j = lane >> 1;
            unsigned long long bb = j == 0 ? b0 : j == 1 ? b1 : j == 2 ? b2 : b3;
            lds[xl][lane] = (lane & 1) ? (unsigned int)(bb >> 32) : (unsigned int)bb;
        }
    }
    __syncthreads();
    int widx = (t & 3) * 2 + (t >> 7);
    int bitpos = (t >> 2) & 31;
    unsigned int w = 0u;
    #pragma unroll
    for (int xl = 0; xl < 32; xl++)
        w |= ((lds[xl][widx] >> bitpos) & 1u) << xl;
    maskT[((size_t)bh * 256 + t) * 128 + (x0 >> 5)] = w;
}

// ---------------- s1 v2: MFMA, split hi/lo bf16 (argmax-safe), single K-step ----
__global__ __launch_bounds__(256) void s1_kernel(
    const float* __restrict__ kq, const float* __restrict__ xkT, float* __restrict__ S)
{
    __shared__ __align__(16) unsigned short Ah[256 * 40];
    __shared__ __align__(16) unsigned short Al[256 * 40];
    __shared__ __align__(16) unsigned short Bh[64 * 40];
    __shared__ __align__(16) unsigned short Bl[64 * 40];
    int bhg = blockIdx.y;
    int x0 = blockIdx.x * 64;
    int id = threadIdx.x;
    int w = id >> 6, l = id & 63, g = l >> 4, kl = l & 15;
    {
        const float* ar = &kq[((size_t)bhg * 256 + id) * 32];
        #pragma unroll
        for (int c8 = 0; c8 < 4; c8++) {
            float4 f0 = *(const float4*)&ar[c8 * 8];
            float4 f1 = *(const float4*)&ar[c8 * 8 + 4];
            float e[8] = {f0.x, f0.y, f0.z, f0.w, f1.x, f1.y, f1.z, f1.w};
            unsigned int hw[4], lw[4];
            #pragma unroll
            for (int j = 0; j < 4; j++) {
                unsigned short h0 = f2b(e[2 * j]), h1 = f2b(e[2 * j + 1]);
                hw[j] = (unsigned int)h0 | ((unsigned int)h1 << 16);
                unsigned short q0 = f2b(e[2 * j] - b2f(h0));
                unsigned short q1 = f2b(e[2 * j + 1] - b2f(h1));
                lw[j] = (unsigned int)q0 | ((unsigned int)q1 << 16);
            }
            *(uint4*)&Ah[id * 40 + c8 * 8] = make_uint4(hw[0], hw[1], hw[2], hw[3]);
            *(uint4*)&Al[id * 40 + c8 * 8] = make_uint4(lw[0], lw[1], lw[2], lw[3]);
        }
    }
    {
        int d = id >> 3, x8 = (id & 7) * 8;
        const float* br = &xkT[((size_t)bhg * 32 + d) * 4096 + x0 + x8];
        float4 b0 = *(const float4*)&br[0];
        float4 b1 = *(const float4*)&br[4];
        float e[8] = {b0.x, b0.y, b0.z, b0.w, b1.x, b1.y, b1.z, b1.w};
        #pragma unroll
        for (int xi = 0; xi < 8; xi++) {
            unsigned short h0 = f2b(e[xi]);
            Bh[(x8 + xi) * 40 + d] = h0;
            Bl[(x8 + xi) * 40 + d] = f2b(e[xi] - b2f(h0));
        }
    }
    __syncthreads();
    bh8 bhf[4], blf[4];
    #pragma unroll
    for (int nt = 0; nt < 4; nt++) {
        bhf[nt] = *(const bh8*)&Bh[(nt * 16 + kl) * 40 + g * 8];
        blf[nt] = *(const bh8*)&Bl[(nt * 16 + kl) * 40 + g * 8];
    }
    fx4 acc[4][4] = {};
    #pragma unroll
    for (int mt = 0; mt < 4; mt++) {
        bh8 ah = *(const bh8*)&Ah[(w * 64 + mt * 16 + kl) * 40 + g * 8];
        bh8 al = *(const bh8*)&Al[(w * 64 + mt * 16 + kl) * 40 + g * 8];
        #pragma unroll
        for (int nt = 0; nt < 4; nt++) {
            acc[mt][nt] = __builtin_amdgcn_mfma_f32_16x16x32_bf16(ah, bhf[nt], acc[mt][nt], 0, 0, 0);
            acc[mt][nt] = __builtin_amdgcn_mfma_f32_16x16x32_bf16(al, bhf[nt], acc[mt][nt], 0, 0, 0);
            acc[mt][nt] = __builtin_amdgcn_mfma_f32_16x16x32_bf16(ah, blf[nt], acc[mt][nt], 0, 0, 0);
        }
    }
    #pragma unroll
    for (int mt = 0; mt < 4; mt++) {
        #pragma unroll
        for (int nt = 0; nt < 4; nt++) {
            #pragma unroll
            for (int r = 0; r < 4; r++) {
                int k = w * 64 + mt * 16 + g * 4 + r;
                S[((size_t)bhg * 256 + k) * 4096 + x0 + nt * 16 + kl] =
                    acc[mt][nt][r] * SCALE;
            }
        }
    }
}

// ---------------- p1 v4: 3-pass softmax (shift-invariant max from pass A) ----
__global__ __launch_bounds__(512) void p1_softmax_kernel(
    float* __restrict__ S,
    const int* __restrict__ rd, const int* __restrict__ polar,
    const unsigned int* __restrict__ maskT,
    const void* __restrict__ dis_emb, const void* __restrict__ polar_emb,
    int* __restrict__ mori, const int* __restrict__ flags)
{
    __shared__ __align__(16) unsigned short rp[4096];  // rd | clamp(polar)<<8
    __shared__ float Tb[8 * 594];                      // per-h disc[r]+pem[j], pitch 9
    int bid = blockIdx.x;
    int b = bid >> 8, k = bid & 255;
    int t = threadIdx.x;
    int bf = flags[1];
    #pragma unroll
    for (int hh = 0; hh < 8; hh++) {
        for (int e = t; e < 528; e += 512) {
            int r = e >> 3, j = e & 7;
            float dv = bf ? b2f(((const unsigned short*)dis_emb)[r * 8 + hh])
                          : ((const float*)dis_emb)[r * 8 + hh];
            float pe = bf ? b2f(((const unsigned short*)polar_emb)[j])
                          : ((const float*)polar_emb)[j];
            Tb[hh * 594 + r * 9 + j] = dv + pe;
        }
    }
    {
        size_t rib = ((size_t)(b * 256 + k)) * 4096 + t * 8;
        int4 r0 = *(const int4*)&rd[rib];
        int4 r1 = *(const int4*)&rd[rib + 4];
        int4 p0 = *(const int4*)&polar[rib];
        int4 p1 = *(const int4*)&polar[rib + 4];
        int rv[8] = {r0.x, r0.y, r0.z, r0.w, r1.x, r1.y, r1.z, r1.w};
        int pv[8] = {p0.x, p0.y, p0.z, p0.w, p1.x, p1.y, p1.z, p1.w};
        unsigned int wds[4];
        #pragma unroll
        for (int j = 0; j < 4; j++) {
            int pa = pv[2 * j] < 0 ? 0 : (pv[2 * j] > 7 ? 7 : pv[2 * j]);
            int pb = pv[2 * j + 1] < 0 ? 0 : (pv[2 * j + 1] > 7 ? 7 : pv[2 * j + 1]);
            unsigned int lo = (unsigned int)(rv[2 * j] | (pa << 8));
            unsigned int hi = (unsigned int)(rv[2 * j + 1] | (pb << 8));
            wds[j] = lo | (hi << 16);
        }
        *(uint4*)&rp[t * 8] = make_uint4(wds[0], wds[1], wds[2], wds[3]);
    }
    __syncthreads();
    int h = t >> 6, lane = t & 63;
    int bhk = (b * 8 + h) * 256 + k;
    float* srow = &S[(size_t)bhk * 4096];
    const float* TbH = &Tb[h * 594];
    const unsigned int* mrow = &maskT[(size_t)bhk * 128];
    float4 sv[16];
    float loc[8] = {0.f, 0.f, 0.f, 0.f, 0.f, 0.f, 0.f, 0.f};
    float mx = -3.4e38f;
    #pragma unroll
    for (int ps = 0; ps < 16; ps++) {
        int x = ps * 256 + lane * 4;
        float4 s4 = *(const float4*)&srow[x];
        unsigned int mw = mrow[x >> 5];
        uint2 rw = *(const uint2*)&rp[x];
        int pvv[4] = {(int)((rw.x >> 8) & 0xFFu), (int)(rw.x >> 24),
                      (int)((rw.y >> 8) & 0xFFu), (int)(rw.y >> 24)};
        float se[4] = {s4.x, s4.y, s4.z, s4.w};
        float lm[4];
        #pragma unroll
        for (int j = 0; j < 4; j++) {
            float a = fabsf(se[j]);
            #pragma unroll
            for (int o = 0; o < 8; o++)
                loc[o] += (pvv[j] == o) ? a : 0.f;
            float lv = ((mw >> ((x & 31) + j)) & 1u) ? -1e6f : se[j];
            lm[j] = lv;
            mx = fmaxf(mx, lv);
        }
        sv[ps] = make_float4(lm[0], lm[1], lm[2], lm[3]);
    }
    #pragma unroll
    for (int o = 0; o < 8; o++) {
        float v = loc[o];
        #pragma unroll
        for (int m = 1; m < 64; m <<= 1) v += __shfl_xor(v, m);
        loc[o] = v;
    }
    #pragma unroll
    for (int m = 1; m < 64; m <<= 1) mx = fmaxf(mx, __shfl_xor(mx, m));
    float best = loc[0]; int mo = 0;
    #pragma unroll
    for (int o = 1; o < 8; o++) if (loc[o] > best) { best = loc[o]; mo = o; }
    if (lane == 0) mori[bhk] = mo;
    float sum = 0.f;
    #pragma unroll
    for (int ps = 0; ps < 16; ps++) {
        int x = ps * 256 + lane * 4;
        uint2 rw = *(const uint2*)&rp[x];
        int rvv[4] = {(int)(rw.x & 0xFFu), (int)((rw.x >> 16) & 0xFFu),
                      (int)(rw.y & 0xFFu), (int)((rw.y >> 16) & 0xFFu)};
        int pvv[4] = {(int)((rw.x >> 8) & 0xFFu), (int)(rw.x >> 24),
                      (int)((rw.y >> 8) & 0xFFu), (int)(rw.y >> 24)};
        float se[4] = {sv[ps].x, sv[ps].y, sv[ps].z, sv[ps].w};
        float ee[4];
        #pragma unroll
        for (int j = 0; j < 4; j++) {
            float bias = TbH[rvv[j] * 9 + ((pvv[j] - mo + 8) & 7)];
            float e = __expf(se[j] + bias - mx);
            ee[j] = e;
            sum += e;
        }
        sv[ps] = make_float4(ee[0], ee[1], ee[2], ee[3]);
    }
    #pragma unroll
    for (int m = 1; m < 64; m <<= 1) sum += __shfl_xor(sum, m);
    float inv = 1.f / sum;
    unsigned short* srow16 = (unsigned short*)(srow + 2048);
    #pragma unroll
    for (int ps = 0; ps < 16; ps++) {
        int x = ps * 256 + lane * 4;
        unsigned int w0 = (unsigned int)f2b(sv[ps].x * inv)
                        | ((unsigned int)f2b(sv[ps].y * inv) << 16);
        unsigned int w1 = (unsigned int)f2b(sv[ps].z * inv)
                        | ((unsigned int)f2b(sv[ps].w * inv) << 16);
        *(uint2*)&srow16[x] = make_uint2(w0, w1);
    }
}

// ---------------- av1 v3: MFMA P@V, wave-private staging, no atomics ----------------
__global__ __launch_bounds__(256) void av1_kernel(
    const float* __restrict__ S, const float* __restrict__ xv, float* __restrict__ k_att)
{
    __shared__ __align__(16) unsigned short Pa[4][16 * 40];
    __shared__ __align__(16) unsigned short Vt[4][32 * 40];
    __shared__ __align__(16) float red[4][512];
    int bhg = blockIdx.y, b = bhg >> 3, h = bhg & 7;
    int k0 = blockIdx.x * 16;
    int id = threadIdx.x;
    int w = id >> 6, l = id & 63, g = l >> 4, kl = l & 15;
    const unsigned short* Pb = (const unsigned short*)S;
    const float* vb = &xv[(size_t)bhg * 4096 * 32];
    int prl = l >> 2, psg = (l & 3) * 8;            // P: 16 rows x 4 lanes (16B)
    size_t pbase = ((size_t)(bhg * 256 + k0 + prl)) * 8192 + 4096;
    int vr = l >> 1, vdh = (l & 1) * 16;            // V: 32 rows x 2 lanes (64B)
    fx4 acc0 = {0.f, 0.f, 0.f, 0.f}, acc1 = {0.f, 0.f, 0.f, 0.f};
    for (int it = 0; it < 32; ++it) {
        int xc = w * 1024 + it * 32;
        uint4 pq = *(const uint4*)&Pb[pbase + xc + psg];
        const float* vp = &vb[(size_t)(xc + vr) * 32 + vdh];
        float4 v0 = *(const float4*)&vp[0];
        float4 v1 = *(const float4*)&vp[4];
        float4 v2 = *(const float4*)&vp[8];
        float4 v3 = *(const float4*)&vp[12];
        *(uint4*)&Pa[w][prl * 40 + psg] = pq;
        float ve[16] = {v0.x, v0.y, v0.z, v0.w, v1.x, v1.y, v1.z, v1.w,
                        v2.x, v2.y, v2.z, v2.w, v3.x, v3.y, v3.z, v3.w};
        #pragma unroll
        for (int i = 0; i < 16; i++)
            Vt[w][(vdh + i) * 40 + vr] = f2b(ve[i]);
        bh8 a  = *(const bh8*)&Pa[w][kl * 40 + g * 8];
        bh8 b0 = *(const bh8*)&Vt[w][kl * 40 + g * 8];
        bh8 b1 = *(const bh8*)&Vt[w][(16 + kl) * 40 + g * 8];
        acc0 = __builtin_amdgcn_mfma_f32_16x16x32_bf16(a, b0, acc0, 0, 0, 0);
        acc1 = __builtin_amdgcn_mfma_f32_16x16x32_bf16(a, b1, acc1, 0, 0, 0);
    }
    #pragma unroll
    for (int r = 0; r < 4; r++) {
        red[w][(g * 4 + r) * 32 + kl]      = acc0[r];
        red[w][(g * 4 + r) * 32 + 16 + kl] = acc1[r];
    }
    __syncthreads();
    #pragma unroll
    for (int rep = 0; rep < 2; rep++) {
        int e = rep * 256 + id;
        float s = red[0][e] + red[1][e] + red[2][e] + red[3][e];
        int kk_ = e >> 5, dd = e & 31;
        k_att[((size_t)(b * 256 + k0 + kk_)) * 256 + h * 32 + dd] = s;
    }
}

// ---------------- fa2 v5: MFMA flash attention (16x16x32 bf16) ----------------
__global__ __launch_bounds__(256) void fa2_kernel(
    const float* __restrict__ kkM, const float* __restrict__ xqT, const float* __restrict__ kvM,
    const int* __restrict__ rd, const int* __restrict__ polar,
    const unsigned int* __restrict__ maskT,
    const void* __restrict__ dis_emb, const void* __restrict__ polar_emb,
    const int* __restrict__ mori, const int* __restrict__ flags,
    float* __restrict__ x_att)
{
    __shared__ __align__(16) unsigned short Qs[128 * 40];   // q bf16 [x][d]
    __shared__ __align__(16) unsigned short Ks[32 * 40];    // k bf16 [k][d] chunk
    __shared__ __align__(16) unsigned short VtT[32 * 40];   // v bf16 [d][k] chunk
    __shared__ __align__(16) unsigned short Pt[4][32 * 40]; // per-wave P bf16 [x][k]
    __shared__ __align__(16) unsigned short rp[32 * 136];   // rd | polar<<8 [k][x]
    __shared__ unsigned short Tb[528];                      // disc[r]+pem[j] bf16
    __shared__ unsigned int mstg[32][4];                    // mask words [k][xword]
    __shared__ unsigned char mo_l[256];
    int bhg = blockIdx.y, b = bhg >> 3, h = bhg & 7;
    int x0 = blockIdx.x * 128;
    int id = threadIdx.x;
    int bf = flags[1];
    int w = id >> 6, l = id & 63, g = l >> 4, kl = l & 15;
    for (int e = id; e < 528; e += 256) {
        int r = e >> 3, j = e & 7;
        float dv = bf ? b2f(((const unsigned short*)dis_emb)[r * 8 + h])
                      : ((const float*)dis_emb)[r * 8 + h];
        float pe = bf ? b2f(((const unsigned short*)polar_emb)[j])
                      : ((const float*)polar_emb)[j];
        Tb[e] = f2b(dv + pe);
    }
    mo_l[id] = (unsigned char)mori[(size_t)bhg * 256 + id];
    #pragma unroll
    for (int rep = 0; rep < 4; rep++) {
        int idx = rep * 256 + id;
        int d = idx >> 5, c = (idx & 31) * 4;
        float4 q4 = *(const float4*)&xqT[((size_t)bhg * 32 + d) * 4096 + x0 + c];
        Qs[(c + 0) * 40 + d] = f2b(q4.x);
        Qs[(c + 1) * 40 + d] = f2b(q4.y);
        Qs[(c + 2) * 40 + d] = f2b(q4.z);
        Qs[(c + 3) * 40 + d] = f2b(q4.w);
    }
    fx4 o00 = {0.f, 0.f, 0.f, 0.f}, o01 = {0.f, 0.f, 0.f, 0.f};
    fx4 o10 = {0.f, 0.f, 0.f, 0.f}, o11 = {0.f, 0.f, 0.f, 0.f};
    float mrow[2][4], lrow[2][4];
    #pragma unroll
    for (int s = 0; s < 2; s++)
        #pragma unroll
        for (int r = 0; r < 4; r++) { mrow[s][r] = -3.0e38f; lrow[s][r] = 0.f; }
    __syncthreads();
    for (int kc = 0; kc < 256; kc += 32) {
        {
            int k = id >> 3, d0 = (id & 7) * 4;
            float4 k4 = *(const float4*)&kkM[((size_t)bhg * 256 + kc + k) * 32 + d0];
            *(unsigned int*)&Ks[k * 40 + d0] =
                (unsigned int)f2b(k4.x) | ((unsigned int)f2b(k4.y) << 16);
            *(unsigned int*)&Ks[k * 40 + d0 + 2] =
                (unsigned int)f2b(k4.z) | ((unsigned int)f2b(k4.w) << 16);
            float4 v4 = *(const float4*)&kvM[((size_t)bhg * 256 + kc + k) * 32 + d0];
            VtT[(d0 + 0) * 40 + k] = f2b(v4.x);
            VtT[(d0 + 1) * 40 + k] = f2b(v4.y);
            VtT[(d0 + 2) * 40 + k] = f2b(v4.z);
            VtT[(d0 + 3) * 40 + k] = f2b(v4.w);
            if (id < 128)
                mstg[id >> 2][id & 3] =
                    maskT[((size_t)bhg * 256 + kc + (id >> 2)) * 128 + (x0 >> 5) + (id & 3)];
        }
        {
            int k = id >> 3, xb = (id & 7) * 16;
            size_t rib = ((size_t)b * 256 + kc + k) * 4096 + x0 + xb;
            __align__(16) unsigned short tmp[16];
            #pragma unroll
            for (int q = 0; q < 4; q++) {
                int4 rv = *(const int4*)&rd[rib + q * 4];
                int4 pq = *(const int4*)&polar[rib + q * 4];
                int pa = pq.x < 0 ? 0 : (pq.x > 7 ? 7 : pq.x);
                int pb = pq.y < 0 ? 0 : (pq.y > 7 ? 7 : pq.y);
                int pc = pq.z < 0 ? 0 : (pq.z > 7 ? 7 : pq.z);
                int pd = pq.w < 0 ? 0 : (pq.w > 7 ? 7 : pq.w);
                tmp[q * 4 + 0] = (unsigned short)(rv.x | (pa << 8));
                tmp[q * 4 + 1] = (unsigned short)(rv.y | (pb << 8));
                tmp[q * 4 + 2] = (unsigned short)(rv.z | (pc << 8));
                tmp[q * 4 + 3] = (unsigned short)(rv.w | (pd << 8));
            }
            *(uint4*)&rp[k * 136 + xb]     = *(const uint4*)&tmp[0];
            *(uint4*)&rp[k * 136 + xb + 8] = *(const uint4*)&tmp[8];
        }
        __syncthreads();
        bh8 aq0 = *(const bh8*)&Qs[(w * 32 + kl) * 40 + g * 8];
        bh8 aq1 = *(const bh8*)&Qs[(w * 32 + 16 + kl) * 40 + g * 8];
        bh8 bk0 = *(const bh8*)&Ks[kl * 40 + g * 8];
        bh8 bk1 = *(const bh8*)&Ks[(16 + kl) * 40 + g * 8];
        fx4 z = {0.f, 0.f, 0.f, 0.f};
        fx4 s00 = __builtin_amdgcn_mfma_f32_16x16x32_bf16(aq0, bk0, z, 0, 0, 0);
        fx4 s01 = __builtin_amdgcn_mfma_f32_16x16x32_bf16(aq0, bk1, z, 0, 0, 0);
        fx4 s10 = __builtin_amdgcn_mfma_f32_16x16x32_bf16(aq1, bk0, z, 0, 0, 0);
        fx4 s11 = __builtin_amdgcn_mfma_f32_16x16x32_bf16(aq1, bk1, z, 0, 0, 0);
        float vv[2][2][4];
        #pragma unroll
        for (int j = 0; j < 2; j++) {
            int k_loc = j * 16 + kl;
            int mo = mo_l[kc + k_loc];
            unsigned int mw = mstg[k_loc][w];
            #pragma unroll
            for (int s = 0; s < 2; s++) {
                #pragma unroll
                for (int r = 0; r < 4; r++) {
                    int bit = s * 16 + g * 4 + r;
                    unsigned short rpv = rp[k_loc * 136 + w * 32 + bit];
                    float bias = b2f(Tb[(rpv & 0xFF) * 8 + ((((int)(rpv >> 8)) - mo + 8) & 7)]);
                    float sc = (s == 0) ? (j == 0 ? s00[r] : s01[r])
                                        : (j == 0 ? s10[r] : s11[r]);
                    vv[s][j][r] = (((mw >> bit) & 1u) ? -1e9f : sc * SCALE) + bias;
                }
            }
        }
        float frs[2][4];
        #pragma unroll
        for (int s = 0; s < 2; s++) {
            #pragma unroll
            for (int r = 0; r < 4; r++) {
                float pm = fmaxf(vv[s][0][r], vv[s][1][r]);
                pm = fmaxf(pm, __shfl_xor(pm, 1));
                pm = fmaxf(pm, __shfl_xor(pm, 2));
                pm = fmaxf(pm, __shfl_xor(pm, 4));
                pm = fmaxf(pm, __shfl_xor(pm, 8));
                float mn = fmaxf(mrow[s][r], pm);
                float e0 = __expf(vv[s][0][r] - mn);
                float e1 = __expf(vv[s][1][r] - mn);
                float cs = e0 + e1;
                cs += __shfl_xor(cs, 1);
                cs += __shfl_xor(cs, 2);
                cs += __shfl_xor(cs, 4);
                cs += __shfl_xor(cs, 8);
                float f = __expf(mrow[s][r] - mn);
                mrow[s][r] = mn;
                lrow[s][r] = lrow[s][r] * f + cs;
                frs[s][r] = f;
                vv[s][0][r] = e0;
                vv[s][1][r] = e1;
            }
        }
        #pragma unroll
        for (int s = 0; s < 2; s++)
            #pragma unroll
            for (int j = 0; j < 2; j++)
                #pragma unroll
                for (int r = 0; r < 4; r++)
                    Pt[w][(s * 16 + g * 4 + r) * 40 + j * 16 + kl] = f2b(vv[s][j][r]);
        #pragma unroll
        for (int r = 0; r < 4; r++) {
            o00[r] *= frs[0][r]; o01[r] *= frs[0][r];
            o10[r] *= frs[1][r]; o11[r] *= frs[1][r];
        }
        bh8 pa0 = *(const bh8*)&Pt[w][kl * 40 + g * 8];
        bh8 pa1 = *(const bh8*)&Pt[w][(16 + kl) * 40 + g * 8];
        bh8 bv0 = *(const bh8*)&VtT[kl * 40 + g * 8];
        bh8 bv1 = *(const bh8*)&VtT[(16 + kl) * 40 + g * 8];
        o00 = __builtin_amdgcn_mfma_f32_16x16x32_bf16(pa0, bv0, o00, 0, 0, 0);
        o01 = __builtin_amdgcn_mfma_f32_16x16x32_bf16(pa0, bv1, o01, 0, 0, 0);
        o10 = __builtin_amdgcn_mfma_f32_16x16x32_bf16(pa1, bv0, o10, 0, 0, 0);
        o11 = __builtin_amdgcn_mfma_f32_16x16x32_bf16(pa1, bv1, o11, 0, 0, 0);
        __syncthreads();
    }
    #pragma unroll
    for (int s = 0; s < 2; s++) {
        #pragma unroll
        for (int r = 0; r < 4; r++) {
            float inv = 1.f / lrow[s][r];
            int x = x0 + w * 32 + s * 16 + g * 4 + r;
            size_t ob = ((size_t)b * 4096 + x) * 256 + h * 32;
            x_att[ob + kl]      = (s == 0 ? o00[r] : o10[r]) * inv;
            x_att[ob + 16 + kl] = (s == 0 ? o01[r] : o11[r]) * inv;
        }
    }
}

// ---------------- final projection ----------------
__global__ __launch_bounds__(256) void proj_kernel(
    const float* __restrict__ A, const void* __restrict__ W, const void* __restrict__ bias,
    float* __restrict__ out, const int* __restrict__ flags)
{
    __shared__ __align__(16) float As[16][68];
    __shared__ __align__(16) float Bs[16][64];
    int bf = flags[1];
    const float* W32 = (const float*)W;
    const unsigned short* W16 = (const unsigned short*)W;
    int m0 = blockIdx.x * 64, n0 = blockIdx.y * 64;
    int id = threadIdx.x, tm = id >> 4, tn = id & 15;
    float acc[4][4] = {};
    for (int k0 = 0; k0 < 256; k0 += 16) {
        int rr = id >> 2, ck = (id & 3) * 4;
        int rk = id >> 4, cn = (id & 15) * 4;
        {
            float4 a4 = *(const float4*)&A[(size_t)(m0 + rr) * 256 + k0 + ck];
            As[ck + 0][rr] = a4.x; As[ck + 1][rr] = a4.y;
            As[ck + 2][rr] = a4.z; As[ck + 3][rr] = a4.w;
        }
        if (bf) {
            uint2 w2 = *(const uint2*)&W16[(size_t)(k0 + rk) * 256 + n0 + cn];
            Bs[rk][cn + 0] = b2f(w2.x & 0xFFFFu); Bs[rk][cn + 1] = b2f(w2.x >> 16);
            Bs[rk][cn + 2] = b2f(w2.y & 0xFFFFu); Bs[rk][cn + 3] = b2f(w2.y >> 16);
        } else {
            *(float4*)&Bs[rk][cn] = *(const float4*)&W32[(size_t)(k0 + rk) * 256 + n0 + cn];
        }
        __syncthreads();
        #pragma unroll
        for (int kk = 0; kk < 16; kk++) {
            float4 a = *(const float4*)&As[kk][tm * 4];
            float4 b = *(const float4*)&Bs[kk][tn * 4];
            float av[4] = {a.x, a.y, a.z, a.w};
            float bv[4] = {b.x, b.y, b.z, b.w};
            #pragma unroll
            for (int i = 0; i < 4; i++)
                #pragma unroll
                for (int j = 0; j < 4; j++)
                    acc[i][j] = fmaf(av[i], bv[j], acc[i][j]);
        }
        __syncthreads();
    }
    #pragma unroll
    for (int i = 0; i < 4; i++) {
        int col = n0 + tn * 4;
        float b0 = bf ? b2f(((const unsigned short*)bias)[col + 0]) : ((const float*)bias)[col + 0];
        float b1 = bf ? b2f(((const unsigned short*)bias)[col + 1]) : ((const float*)bias)[col + 1];
        float b2v = bf ? b2f(((const unsigned short*)bias)[col + 2]) : ((const float*)bias)[col + 2];
        float b3 = bf ? b2f(((const unsigned short*)bias)[col + 3]) : ((const float*)bias)[col + 3];
        float4 o = make_float4(acc[i][0] + b0, acc[i][1] + b1, acc[i][2] + b2v, acc[i][3] + b3);
        *(float4*)&out[(size_t)(m0 + tm * 4 + i) * 256 + col] = o;
    }
}

extern "C" void kernel_launch(void* const* d_in, const int* in_sizes, int n_in,
                              void* d_out, int out_size, void* d_ws, size_t ws_size,
                              hipStream_t stream) {
    (void)in_sizes; (void)n_in; (void)out_size; (void)ws_size;
    const void* x         = d_in[0];
    const void* kern      = d_in[1];
    const int*  rd        = (const int*)d_in[2];
    const int*  polar     = (const int*)d_in[3];
    const void* amask     = d_in[4];
    const void* w_qkv     = d_in[5];
    const void* w_proj    = d_in[6];
    const void* b_proj    = d_in[7];
    const void* polar_emb = d_in[8];
    const void* dis_emb   = d_in[9];
    float* out = (float*)d_out;

    float* ws = (float*)d_ws;
    float* S     = ws + OFF_S;
    float* xqT   = ws + OFF_XQT;
    float* xv    = ws + OFF_XV;
    float* xkT   = ws + OFF_XKT;
    float* kq    = ws + OFF_KQ;
    float* kkM   = ws + OFF_KK;
    float* kvM   = ws + OFF_KV;
    float* k_att = ws + OFF_KATT;
    float* x_att = ws + OFF_XATT;
    unsigned int* maskT = (unsigned int*)(ws + OFF_MT);
    int* mori  = (int*)(ws + OFF_MORI);
    int* flags = (int*)(ws + OFF_FLAG);

    detect_kernel<<<2, 256, 0, stream>>>((const unsigned int*)amask, (const unsigned int*)x, flags);
    qkv128_kernel<<<dim3(128, 12), 256, 0, stream>>>(x, w_qkv, xqT, xkT, xv, flags);
    qkv_kernel<<<dim3(16, 12), 256, 0, stream>>>(kern, w_qkv, kq, kkM, kvM, flags);
    maskpack_kernel<<<4096, 256, 0, stream>>>(amask, maskT, flags);

    // FULL-batch pipeline (k_att fully written by av1 v3 -> no memset)
    s1_kernel<<<dim3(64, 32), 256, 0, stream>>>(kq, xkT, S);
    p1_softmax_kernel<<<1024, 512, 0, stream>>>(S, rd, polar, maskT, dis_emb, polar_emb,
                                                mori, flags);
    av1_kernel<<<dim3(16, 32), 256, 0, stream>>>(S, xv, k_att);
    fa2_kernel<<<dim3(32, 32), 256, 0, stream>>>(kkM, xqT, kvM, rd, polar, maskT,
                                                 dis_emb, polar_emb, mori, flags, x_att);

    proj_kernel<<<dim3(256, 4), 256, 0, stream>>>(x_att, w_proj, b_proj, out, flags);
    proj_kernel<<<dim3(16, 4), 256, 0, stream>>>(k_att, w_proj, b_proj, out + 4194304, flags);
}